// Round 4
// baseline (195.951 us; speedup 1.0000x reference)
//
#include <hip/hip_runtime.h>

// MRPCEN: multi-rate PCEN. x:(32,128,2000) f32 -> out:(32,4,128,2000) f32.
// One wave per (b,f) row; EMA via affine wave-scan; epilogue fused.
//
// R3/R4: LDS eliminated entirely. Each lane owns a contiguous 32-elem chunk:
//  - load: 8x float4 per lane (lane stride 128 B; L2/L3 serves full lines)
//  - store: 8x float4 per lane; each 128-B line fully written by one lane
//    across consecutive stores -> L2 merges, HBM writes stay ~128 MB.
//  - no barriers, no ds-ops; VGPR-bound occupancy.
//  - exp2f/log2f (lower to single v_exp_f32/v_log_f32; hw is base-2).
//    NOTE: __exp2f/__log2f collide with glibc math.h on this toolchain.

#define NT    4
#define TLEN  2000
#define FDIM  128
#define CHUNK 32
#define WPB   4   // waves per block (independent; no shared state)

__global__ __launch_bounds__(256) void mrpcen_kernel(
    const float* __restrict__ x,
    const float* __restrict__ log_alpha,
    const float* __restrict__ log_delta,
    const float* __restrict__ log_r,
    float* __restrict__ out,
    int rows)
{
    const int w    = threadIdx.x >> 6;
    const int lane = threadIdx.x & 63;
    const int row  = blockIdx.x * WPB + w;          // [0, 4096)
    if (row >= rows) return;                        // no barriers: safe
    const int b = row >> 7;
    const int f = row & (FDIM - 1);

    // ---- per-lane chunk load: 8x float4, guarded tail ----
    float xr[CHUNK];
    const float* xrow = x + (size_t)row * TLEN;
    const int base = lane * CHUNK;
#pragma unroll
    for (int q = 0; q < CHUNK / 4; ++q) {
        int pos = base + q * 4;
        float4 v = (pos < TLEN) ? ((const float4*)xrow)[pos >> 2]
                                : make_float4(0.f, 0.f, 0.f, 0.f);
        xr[q * 4 + 0] = v.x; xr[q * 4 + 1] = v.y;
        xr[q * 4 + 2] = v.z; xr[q * 4 + 3] = v.w;
    }

    const float alpha = __expf(log_alpha[f]);       // wave-uniform broadcast
    const float delta = __expf(log_delta[f]);
    const float rr    = __expf(log_r[f]);
    const float dr    = exp2f(rr * log2f(delta));   // delta^r
    const float eps   = 1e-5f;
    const float nalpha = -alpha;

    const float tvals[NT] = {4.f, 16.f, 64.f, 256.f};

#pragma unroll 1
    for (int ti = 0; ti < NT; ++ti) {
        const float t  = tvals[ti];
        const float s  = (sqrtf(1.f + 4.f * t * t) - 1.f) / (2.f * t * t);
        const float cs = 1.f - s;

        // ---- A closed form (product of per-elem coeffs over chunk) ----
        // lane 0: elem 0 has a=0 -> A=0. lanes 1..61: cs^32.
        // lane 62: 16 live + 16 identity -> cs^16. lane 63: all identity -> 1.
        float c2  = cs * cs, c4 = c2 * c2, c8 = c4 * c4;
        float c16 = c8 * c8, c32 = c16 * c16;
        float A = (lane == 0) ? 0.f : (lane < 62) ? c32 : (lane == 62) ? c16 : 1.f;

        // ---- B: zero-init prefix over chunk (serial fma spine) ----
        float B = 0.f;
#pragma unroll
        for (int j = 0; j < CHUNK; ++j) {
            int pos  = base + j;
            float a  = (pos < TLEN) ? cs : 1.0f;
            float bb = (pos < TLEN) ? s * xr[j] : 0.0f;
            if (pos == 0) { a = 0.0f; bb = xr[j]; }
            B = fmaf(a, B, bb);
        }

        // ---- wave inclusive scan of affine maps ----
#pragma unroll
        for (int off = 1; off < 64; off <<= 1) {
            float Ap = __shfl_up(A, off, 64);
            float Bp = __shfl_up(B, off, 64);
            if (lane >= off) {
                B = fmaf(A, Bp, B);
                A = A * Ap;
            }
        }
        float m = __shfl_up(B, 1, 64);              // incoming state for chunk

        // ---- replay + fused pcen epilogue, float4 stores ----
        float* gout = out + ((size_t)(b * NT + ti) * FDIM + f) * TLEN;
        float o4[4];
#pragma unroll
        for (int j = 0; j < CHUNK; ++j) {
            int pos  = base + j;
            float a  = (pos < TLEN) ? cs : 1.0f;
            float bb = (pos < TLEN) ? s * xr[j] : 0.0f;
            if (pos == 0) { a = 0.0f; bb = xr[j]; }
            m = fmaf(a, m, bb);
            // (eps+m)^-alpha
            float smooth = exp2f(nalpha * log2f(eps + m));
            float v      = fmaf(xr[j], smooth, delta);
            o4[j & 3]    = exp2f(rr * log2f(v)) - dr;   // v^r - delta^r
            if ((j & 3) == 3) {
                int p0 = base + (j & ~3);
                if (p0 < TLEN)
                    ((float4*)gout)[p0 >> 2] =
                        make_float4(o4[0], o4[1], o4[2], o4[3]);
            }
        }
    }
}

extern "C" void kernel_launch(void* const* d_in, const int* in_sizes, int n_in,
                              void* d_out, int out_size, void* d_ws, size_t ws_size,
                              hipStream_t stream) {
    const float* x  = (const float*)d_in[0];
    const float* la = (const float*)d_in[1];
    const float* ld = (const float*)d_in[2];
    const float* lr = (const float*)d_in[3];
    float* out = (float*)d_out;

    const int rows   = in_sizes[0] / TLEN;          // 4096
    const int blocks = (rows + WPB - 1) / WPB;      // 1024
    hipLaunchKernelGGL(mrpcen_kernel, dim3(blocks), dim3(256), 0, stream,
                       x, la, ld, lr, out, rows);
}

// Round 5
// 172.369 us; speedup vs baseline: 1.1368x; 1.1368x over previous
//
#include <hip/hip_runtime.h>

// MRPCEN: multi-rate PCEN. x:(32,128,2000) f32 -> out:(32,4,128,2000) f32.
//
// R5: one wave per OUTPUT row (b,ti,f) -> 16384 independent wave-jobs.
//  - per-lane direct float4 global loads (R4-proven; FETCH ~25-45 MB, L3 serves)
//  - EMA via affine wave-scan; uniform coefficients (zero-padded xr; only
//    element 0 is special, handled by two lane-0 selects -- positions >=2000
//    only affect lane 63's never-stored outputs)
//  - stores through LDS stage (+33 stride, conflict-free) with float4
//    coalesced drain: R1 measured EXACTLY 128 MB HBM writes this way,
//    vs R4's direct per-lane stores which ballooned to 218 MB (partial-line
//    L2 evictions).
//  - exactly ONE __syncthreads per wave.

#define NT      4
#define TLEN    2000
#define FDIM    128
#define CHUNK   32
#define LSTRIDE 33               // bank = (lane + j) % 32 -> 2-way = free
#define ROWPAD  (64 * LSTRIDE)   // 2112 floats = 8448 B per wave
#define WPB     4                // 33792 B/block -> 4 blocks/CU = 16 waves/CU

__global__ __launch_bounds__(256, 4) void mrpcen_kernel(
    const float* __restrict__ x,
    const float* __restrict__ log_alpha,
    const float* __restrict__ log_delta,
    const float* __restrict__ log_r,
    float* __restrict__ out,
    int nrows)
{
    __shared__ float stage[WPB][ROWPAD];

    const int w    = threadIdx.x >> 6;
    const int lane = threadIdx.x & 63;
    const int row2 = blockIdx.x * WPB + w;          // [0, 16384)
    if (row2 >= nrows) return;
    const int f  = row2 & (FDIM - 1);
    const int ti = (row2 >> 7) & (NT - 1);
    const int b  = row2 >> 9;

    // ---- per-lane chunk load: 8x float4, zero-padded tail ----
    float xr[CHUNK];
    const float* xrow = x + (size_t)(b * FDIM + f) * TLEN;
    const int base = lane * CHUNK;
#pragma unroll
    for (int q = 0; q < CHUNK / 4; ++q) {
        int pos = base + q * 4;                     // TLEN%4==0: whole-float4 guard
        float4 v = (pos < TLEN) ? ((const float4*)xrow)[pos >> 2]
                                : make_float4(0.f, 0.f, 0.f, 0.f);
        xr[q * 4 + 0] = v.x; xr[q * 4 + 1] = v.y;
        xr[q * 4 + 2] = v.z; xr[q * 4 + 3] = v.w;
    }

    const float alpha = __expf(log_alpha[f]);       // uniform broadcast loads
    const float delta = __expf(log_delta[f]);
    const float rr    = __expf(log_r[f]);
    const float dr    = exp2f(rr * log2f(delta));   // delta^r
    const float nal   = -alpha;
    const float eps   = 1e-5f;

    const float tv = (ti == 0) ? 4.f : (ti == 1) ? 16.f : (ti == 2) ? 64.f : 256.f;
    const float s  = (sqrtf(1.f + 4.f * tv * tv) - 1.f) / (2.f * tv * tv);
    const float cs = 1.f - s;

    // ---- A closed form: cs^32 (lane 0: elem 0 has a=0 -> A=0) ----
    float c2 = cs * cs, c4 = c2 * c2, c8 = c4 * c4, c16 = c8 * c8, c32 = c16 * c16;
    float A = (lane == 0) ? 0.f : c32;

    // ---- B chain, uniform coeffs; lane0 elem0 is (a=0, b=x0) ----
    float B = (lane == 0) ? xr[0] : s * xr[0];
#pragma unroll
    for (int j = 1; j < CHUNK; ++j)
        B = fmaf(cs, B, s * xr[j]);

    // ---- wave inclusive scan of affine maps ----
#pragma unroll
    for (int off = 1; off < 64; off <<= 1) {
        float Ap = __shfl_up(A, off, 64);
        float Bp = __shfl_up(B, off, 64);
        if (lane >= off) { B = fmaf(A, Bp, B); A *= Ap; }
    }
    float m = __shfl_up(B, 1, 64);                  // incoming state
    if (lane == 0) m = xr[0];                       // fma(cs,x0,s*x0) == x0

    // ---- replay + fused pcen epilogue -> LDS stage ----
#pragma unroll
    for (int j = 0; j < CHUNK; ++j) {
        m = fmaf(cs, m, s * xr[j]);
        float smooth = exp2f(nal * log2f(eps + m)); // (eps+m)^-alpha
        float v      = fmaf(xr[j], smooth, delta);
        stage[w][lane * LSTRIDE + j] = exp2f(rr * log2f(v)) - dr;
    }
    __syncthreads();

    // ---- drain: 4x ds_read_b32 + coalesced float4 store per round ----
    float* gout = out + (size_t)row2 * TLEN;
#pragma unroll
    for (int k = 0; k < 8; ++k) {
        int p0 = k * 256 + lane * 4;                // contiguous across lanes
        if (p0 < TLEN) {
            int r = p0 >> 5, c = p0 & 31;           // c in {0,4,...,28}: no row cross
            float a0 = stage[w][r * LSTRIDE + c + 0];
            float a1 = stage[w][r * LSTRIDE + c + 1];
            float a2 = stage[w][r * LSTRIDE + c + 2];
            float a3 = stage[w][r * LSTRIDE + c + 3];
            ((float4*)gout)[p0 >> 2] = make_float4(a0, a1, a2, a3);
        }
    }
}

extern "C" void kernel_launch(void* const* d_in, const int* in_sizes, int n_in,
                              void* d_out, int out_size, void* d_ws, size_t ws_size,
                              hipStream_t stream) {
    const float* x  = (const float*)d_in[0];
    const float* la = (const float*)d_in[1];
    const float* ld = (const float*)d_in[2];
    const float* lr = (const float*)d_in[3];
    float* out = (float*)d_out;

    const int nrows  = out_size / TLEN;             // 16384 output rows
    const int blocks = (nrows + WPB - 1) / WPB;     // 4096
    hipLaunchKernelGGL(mrpcen_kernel, dim3(blocks), dim3(256), 0, stream,
                       x, la, ld, lr, out, nrows);
}